// Round 18
// baseline (72.555 us; speedup 1.0000x reference)
//
#include <hip/hip_runtime.h>

// ACT-R activation recurrence — async spine + 3-diagonal decoupled chain.
// s_i = sum_{j<i} ((t_i-t_j)*H)^(-decay_j),  decay_j = w0 + w1*s_j  (s_0=0)
// (reference's max(diff*H,1) never binds: min gap 0.05 days * 2160 = 108)
// out[i-1,b] = sigmoid((ln(s_i)-TAU)/S), i=1..L-1.
//
// Identity: diff^(-decay_j) = exp2(q_ij*alpha_j), q_ij = -w1*log2(diff_ij),
// alpha = s + w0/w1 > 0; masked q = -1e30 -> term 0.
//
// R18 chain: vector band holds only cols j <= l-4; rows' three nearest
// predecessors go scalar-side: sigma_i = PP_i + exp2(qd1_i*sigma_{i-1}),
// PP_i = alpha[i] (rdlane, 2-step-old write: col i-4 applied at step i-3,
// and the rdlane is issued BEFORE this step's band write) + e2_i + e3_i
// (exp2(qd2/qd3 * sigma), computed 1-2 steps early, off-path).
// Band q streams from LDS (1 ds_read_b32 per link, 3 cols ahead, off-path)
// -> no 16-quad residency problem, ~25 live regs by design.
// Critical path per link: mul -> exp2 -> add(+add)  (no cross-lane hazard).
// Spine: R13/R16 barrier-free flags; wave4 idle (SIMD0 = chain alone);
// 6 workers: strip (exact) + Chebyshev-8 far tiles + build next tables.

constexpr int   L  = 1024;
constexpr int   B  = 256;
constexpr int   T  = 64;
constexpr int   NT = 512;    // 8 waves: wave0 chain, wave4 idle, 6 workers

constexpr float H_CONST = 86400.0f * 0.025f;   // 2160
constexpr float TAU_C   = -0.704205679427144f;
constexpr float S_C     = 0.254893976981164f;
constexpr float LN2     = 0.69314718055994530942f;
constexpr float LOG2E   = 1.4426950408889634074f;
constexpr float BIGNEG  = -1e30f;

// cos(k*pi/16)
constexpr float CC1 = 0.98078528040323044913f;
constexpr float CC2 = 0.92387953251128675613f;
constexpr float CC3 = 0.83146961230254523708f;
constexpr float CC4 = 0.70710678118654752440f;
constexpr float CC5 = 0.55557023301960222474f;
constexpr float CC6 = 0.38268343236508977173f;
constexpr float CC7 = 0.19509032201612826785f;

__device__ static const float UNODE[8] =
  { CC1, CC3, CC5, CC7, -CC7, -CC5, -CC3, -CC1 };

__device__ __forceinline__ float flog2(float x) { return __builtin_amdgcn_logf(x); }
__device__ __forceinline__ float fexp2(float x) { return __builtin_amdgcn_exp2f(x); }
__device__ __forceinline__ float rdlane(float v, int l) {
    return __uint_as_float(__builtin_amdgcn_readlane(__float_as_uint(v), l));
}

// Chain step J (1..63), produces sigma_J.
// entering: sig1 = sigma_{J-1}; PPf = base/band[J] + e2_J + e3_J;
//           sQ1 = qd1[J]; sQ2 = qd2[J+1]; sQ3 = qd3[J+2];
//           QC holds band col J-1; e3p = e3_{J+1}.
// rdlane(alpha, J+1) needs cols <= J-3: col J-3 was applied at step J-2
// (2 steps ago) and this step's band write comes AFTER the rdlane.
#define CSTEP(QC, J) {                                            \
    const float pa_  = rdlane(alpha, ((J) + 1) & 63);             \
    alpha += fexp2((QC) * sig1);            /* band col J-1 */    \
    (QC) = qbB[(((J) + 2) & 63) * 64 + lane];  /* col J+2 */      \
    const float t_   = fexp2(sQ1 * sig1);   /* PATH */            \
    const float e2n_ = fexp2(sQ2 * sig1);   /* e2_{J+1} */        \
    const float e3n_ = fexp2(sQ3 * sig1);   /* e3_{J+2} */        \
    const float ns_  = PPf + t_;            /* PATH */            \
    sigv = (lane == (J)) ? ns_ : sigv;                            \
    PPf  = (pa_ + e2n_) + e3p;                                    \
    e3p  = e3n_;                                                  \
    sQ1 = rdlane(qd1v, ((J) + 1) & 63);                           \
    sQ2 = rdlane(qd2v, ((J) + 2) & 63);                           \
    sQ3 = rdlane(qd3v, ((J) + 3) & 63);                           \
    sig1 = ns_; }

#define C3(J) CSTEP(qc0, J) CSTEP(qc1, (J)+1) CSTEP(qc2, (J)+2)

__global__ __launch_bounds__(NT)
void actr_kernel(const float* __restrict__ sp, const float* __restrict__ w,
                 float* __restrict__ out)
{
    __shared__ float  tH[L];
    __shared__ float  acc[L];        // strip + far partial sums
    __shared__ float2 col[L];        // finalized columns {t_j, -decay_j}
    __shared__ float  qB[2][T * T];  // band q, COL-major [j*64+l], j<=l-4
    __shared__ float  qd1a[2][T];    // q_{l,l-1}
    __shared__ float  qd2a[2][T];    // q_{l,l-2}
    __shared__ float  qd3a[2][T];    // q_{l,l-3}
    __shared__ int    COLF[16];
    __shared__ int    DONE[16];

    const int bid  = blockIdx.x;
    const int b    = (bid & 7) * 32 + (bid >> 3);   // XCD write-coalescing
    const int tid  = threadIdx.x;
    const int lane = tid & 63;
    const int wv   = tid >> 6;       // 0..7
    const float w0  = w[0];
    const float w1  = w[1];
    const float CSH = w0 / w1;

    for (int i = tid; i < L; i += NT) {
        tH[i]  = sp[i * B + b] * H_CONST;
        acc[i] = 0.0f;
    }
    if (tid < 16) { COLF[tid] = 0; DONE[tid] = 0; }
    if (tid < 3) {
        for (int blk = 0; blk < 2; ++blk) {
            if (tid == 0) qd1a[blk][0] = BIGNEG;
            if (tid <  2) qd2a[blk][tid] = BIGNEG;
            qd3a[blk][tid] = BIGNEG;
        }
    }
    __syncthreads();

    // prologue (all 8 waves): build qB/qd for blocks 0 and 1
    for (int blk = 0; blk < 2; ++blk) {
        const int base = blk * 64;
        for (int f = tid; f < T * T; f += NT) {
            const int j = f >> 6, l2 = f & 63;
            const float val = -w1 * flog2(tH[base + l2] - tH[base + j]);
            qB[blk][j * 64 + l2] = (l2 >= j + 4) ? val : BIGNEG;
            if (l2 - j == 1) qd1a[blk][l2] = val;
            if (l2 - j == 2) qd2a[blk][l2] = val;
            if (l2 - j == 3) qd3a[blk][l2] = val;
        }
    }
    __syncthreads();    // last barrier — none in the main loop

    if (wv == 0) {
        // ================= chain wave (SIMD0, alone) =================
        volatile int* vDONE = DONE;
        for (int k = 0; k < 16; ++k) {
            const int I0 = k * T;
            const int target = (k == 0) ? 0 : (k == 1) ? 6 : k + 11;
            while (vDONE[k] < target) __builtin_amdgcn_s_sleep(2);
            asm volatile("" ::: "memory");

            const float* qbB = &qB[k & 1][0];
            float qc0 = qbB[0 * 64 + lane];   // col 0
            float qc1 = qbB[1 * 64 + lane];   // col 1
            float qc2 = qbB[2 * 64 + lane];   // col 2
            const float qd1v = qd1a[k & 1][lane];
            const float qd2v = qd2a[k & 1][lane];
            const float qd3v = qd3a[k & 1][lane];

            float alpha = acc[I0 + lane] + CSH;   // base; band cols added below
            float sigv  = alpha;                  // lane 0: sigma_0 = base_0
            float sig1  = rdlane(alpha, 0);       // sigma_0
            float PPf   = rdlane(alpha, 1);       // base_1 (e2_1 = e3_1 = 0)
            float e3p   = 0.0f;                   // e3_2 = 0 (qd3_2 masked)
            float sQ1 = rdlane(qd1v, 1);
            float sQ2 = rdlane(qd2v, 2);
            float sQ3 = rdlane(qd3v, 3);

            __builtin_amdgcn_s_setprio(1);
            C3( 1) C3( 4) C3( 7) C3(10) C3(13) C3(16) C3(19)
            C3(22) C3(25) C3(28) C3(31) C3(34) C3(37) C3(40)
            C3(43) C3(46) C3(49) C3(52) C3(55) C3(58) C3(61)
            __builtin_amdgcn_s_setprio(0);

            const int r = I0 + lane;
            col[r] = make_float2(tH[r], -w1 * sigv);
            asm volatile("" ::: "memory");
            if (lane == 0) atomicExch(&COLF[k], 1);     // release

            if (r > 0) {
                const float act = flog2(sigv - CSH) * LN2;      // ln(s_r)
                const float e   = fexp2((TAU_C - act) * (LOG2E / S_C));
                out[(r - 1) * B + b] = 1.0f / (1.0f + e);
            }
        }
    } else if (wv != 4) {
        // ================= 6 worker waves (never on SIMD0) =================
        const int p = (wv < 4) ? (wv - 1) : (wv - 2);   // 0..5
        volatile int* vCOLF = COLF;
        for (int c = 0; c < 15; ++c) {
            while (vCOLF[c] == 0) __builtin_amdgcn_s_sleep(2);
            asm volatile("" ::: "memory");

            // --- strip (c+1, c): exact; 16 thr/row, rowgroups p+6m ---
            {
                const float2* cb = &col[c * 64];
                #pragma unroll
                for (int m = 0; m < 3; ++m) {
                    const int g = p + 6 * m;          // rowgroup 0..15
                    if (g < 16) {
                        const int rl = 4 * g + (lane >> 4);
                        const int c4 = lane & 15;
                        const float my_t = tH[(c + 1) * 64 + rl];
                        float s = 0.0f;
                        #pragma unroll
                        for (int u = 0; u < 4; ++u) {
                            const float2 cj = cb[c4 + 16 * u];
                            s += fexp2(cj.y * flog2(my_t - cj.x));
                        }
                        s += __shfl_xor(s, 1);
                        s += __shfl_xor(s, 2);
                        s += __shfl_xor(s, 4);
                        s += __shfl_xor(s, 8);
                        if (c4 == 0) atomicAdd(&acc[(c + 1) * 64 + rl], s);
                    }
                }
                asm volatile("" ::: "memory");
                if (lane == 0) atomicAdd(&DONE[c + 1], 1);
            }

            // --- far tiles (r, c) via Chebyshev-8: r = c+2+p+6m ---
            #pragma unroll
            for (int t2 = 0; t2 < 3; ++t2) {
                const int r = c + 2 + p + 6 * t2;
                if (r <= 15) {
                    const int m  = lane >> 3;
                    const int g  = lane & 7;
                    const float At  = tH[r * 64];
                    const float Bt  = tH[r * 64 + 63];
                    const float mid = 0.5f * (At + Bt);
                    const float hf  = 0.5f * (Bt - At);
                    const float xm  = fmaf(hf, UNODE[m], mid);
                    const float2* cb = &col[c * 64 + g * 8];
                    float gm = 0.0f;
                    #pragma unroll
                    for (int jj = 0; jj < 8; ++jj) {
                        const float2 cj = cb[jj];
                        gm += fexp2(cj.y * flog2(xm - cj.x));
                    }
                    gm += __shfl_xor(gm, 1);
                    gm += __shfl_xor(gm, 2);
                    gm += __shfl_xor(gm, 4);
                    const float g0 = rdlane(gm,  0), g1 = rdlane(gm,  8);
                    const float g2 = rdlane(gm, 16), g3 = rdlane(gm, 24);
                    const float g4 = rdlane(gm, 32), g5 = rdlane(gm, 40);
                    const float g6 = rdlane(gm, 48), g7 = rdlane(gm, 56);
                    const float u0 = g0 + g7, u1 = g1 + g6;
                    const float u2s = g2 + g5, u3 = g3 + g4;
                    const float d0 = g0 - g7, d1 = g1 - g6;
                    const float d2 = g2 - g5, d3 = g3 - g4;
                    const float a0 = 0.125f * (u0 + u1 + u2s + u3);
                    const float a2 = 0.25f * (CC2 * (u0 - u3) + CC6 * (u1 - u2s));
                    const float a4 = 0.25f * CC4 * (u0 - u1 - u2s + u3);
                    const float a6 = 0.25f * (CC6 * (u0 - u3) - CC2 * (u1 - u2s));
                    const float a1 = 0.25f * (CC1*d0 + CC3*d1 + CC5*d2 + CC7*d3);
                    const float a3 = 0.25f * (CC3*d0 - CC7*d1 - CC1*d2 - CC5*d3);
                    const float a5 = 0.25f * (CC5*d0 - CC1*d1 + CC7*d2 + CC3*d3);
                    const float a7 = 0.25f * (CC7*d0 - CC5*d1 + CC3*d2 - CC1*d3);
                    const int   i  = r * 64 + lane;
                    const float u  = (tH[i] - mid) * __builtin_amdgcn_rcpf(hf);
                    const float uu = u + u;
                    float bk1 = a7;
                    float bk  = fmaf(uu, a7, a6);
                    float t3v;
                    t3v = fmaf(uu, bk, a5) - bk1; bk1 = bk; bk = t3v;
                    t3v = fmaf(uu, bk, a4) - bk1; bk1 = bk; bk = t3v;
                    t3v = fmaf(uu, bk, a3) - bk1; bk1 = bk; bk = t3v;
                    t3v = fmaf(uu, bk, a2) - bk1; bk1 = bk; bk = t3v;
                    t3v = fmaf(uu, bk, a1) - bk1; bk1 = bk; bk = t3v;
                    atomicAdd(&acc[i], fmaf(u, bk, a0) - bk1);
                    asm volatile("" ::: "memory");
                    if (lane == 0) atomicAdd(&DONE[r], 1);
                }
            }

            // --- build qB/qd for block c+2 (timestamps only) ---
            if (c <= 13) {
                const int blk = c + 2;
                const int sl  = blk & 1;
                const float vtB = tH[blk * 64 + lane];
                if (p == 0) {
                    if (lane == 0) qd1a[sl][0] = BIGNEG;
                    if (lane <  2) qd2a[sl][lane] = BIGNEG;
                    if (lane <  3) qd3a[sl][lane] = BIGNEG;
                }
                float* qn = &qB[sl][0];
                #pragma unroll
                for (int m2 = 0; m2 < 11; ++m2) {
                    const int j = p + 6 * m2;
                    if (j < 64) {
                        const float tcol = rdlane(vtB, j);
                        const float val  = -w1 * flog2(vtB - tcol);
                        qn[j * 64 + lane] = (lane >= j + 4) ? val : BIGNEG;
                        if (lane == j + 1) qd1a[sl][lane] = val;
                        if (lane == j + 2) qd2a[sl][lane] = val;
                        if (lane == j + 3) qd3a[sl][lane] = val;
                    }
                }
                asm volatile("" ::: "memory");
                if (lane == 0) atomicAdd(&DONE[blk], 1);
            }
        }
    }
    // wave 4: idle — SIMD0 belongs to the chain
}

extern "C" void kernel_launch(void* const* d_in, const int* in_sizes, int n_in,
                              void* d_out, int out_size, void* d_ws, size_t ws_size,
                              hipStream_t stream) {
    const float* sp = (const float*)d_in[0];
    const float* w  = (const float*)d_in[1];
    float* out      = (float*)d_out;
    actr_kernel<<<dim3(B), dim3(NT), 0, stream>>>(sp, w, out);
}

// Round 19
// 45.865 us; speedup vs baseline: 1.5819x; 1.5819x over previous
//
#include <hip/hip_runtime.h>

// ACT-R activation recurrence — async spine, chain-folded strip, isolated SIMD0.
// s_i = sum_{j<i} ((t_i-t_j)*H)^(-decay_j),  decay_j = w0 + w1*s_j  (s_0=0)
// (reference's max(diff*H,1) never binds: min gap 0.05 days * 2160 = 108)
// out[i-1,b] = sigmoid((ln(s_i)-TAU)/S), i=1..L-1.
//
// Identity: diff^(-decay_j) = exp2(q_ij*alpha_j), q_ij = -w1*log2(diff_ij),
// alpha = s + w0/w1 > 0; masked q = -1e30 -> term 0.
//
// FINAL (best of 18 rounds, 45.8us): the wall is the 1024-deep serial link
// rdlane -> mul -> exp2 -> add at ~105 cyc/link (measured invariant across
// contended/isolated/decoupled variants); all parallel work fits under it.
//  wave 0 (SIMD0, alone - wave 4 idle): 16 blocks back-to-back; per block,
//    64-step chain; the strip into block k+1 is FOLDED into the chain
//    (beta += exp2(qS_j * sigma_j)) -- free, the link is latency-bound.
//  waves 1-3,5-7: Chebyshev-8 far tiles (r-c>=2; 8x64 node evals -> DCT ->
//    Clenshaw, ~8x fewer transcendentals) + next-block q tables.
// Barrier-free handoff via LDS flags (release: col[] write -> COLF flag).

constexpr int   L  = 1024;
constexpr int   B  = 256;
constexpr int   T  = 64;
constexpr int   NT = 512;    // 8 waves: wave0 chain, wave4 idle, 6 workers

constexpr float H_CONST = 86400.0f * 0.025f;   // 2160
constexpr float TAU_C   = -0.704205679427144f;
constexpr float S_C     = 0.254893976981164f;
constexpr float LN2     = 0.69314718055994530942f;
constexpr float LOG2E   = 1.4426950408889634074f;
constexpr float BIGNEG  = -1e30f;

// cos(k*pi/16)
constexpr float CC1 = 0.98078528040323044913f;
constexpr float CC2 = 0.92387953251128675613f;
constexpr float CC3 = 0.83146961230254523708f;
constexpr float CC4 = 0.70710678118654752440f;
constexpr float CC5 = 0.55557023301960222474f;
constexpr float CC6 = 0.38268343236508977173f;
constexpr float CC7 = 0.19509032201612826785f;

__device__ static const float UNODE[8] =
  { CC1, CC3, CC5, CC7, -CC7, -CC5, -CC3, -CC1 };

typedef float f32x4 __attribute__((ext_vector_type(4)));

__device__ __forceinline__ float flog2(float x) { return __builtin_amdgcn_logf(x); }
__device__ __forceinline__ float fexp2(float x) { return __builtin_amdgcn_exp2f(x); }
__device__ __forceinline__ float rdlane(float v, int l) {
    return __uint_as_float(__builtin_amdgcn_readlane(__float_as_uint(v), l));
}

#define LOADQ(p0, p1, p2, p3, QB, c)                                \
    p0 = *(const f32x4*)((QB) + 4 * ((4 * (c) + 0) ^ xk));          \
    p1 = *(const f32x4*)((QB) + 4 * ((4 * (c) + 1) ^ xk));          \
    p2 = *(const f32x4*)((QB) + 4 * ((4 * (c) + 2) ^ xk));          \
    p3 = *(const f32x4*)((QB) + 4 * ((4 * (c) + 3) ^ xk));

// one chain step: sigma_J broadcast; band (alpha, this block) + strip (beta,
// next block) updates. Lane l's alpha is final after step l (qT masks j>=l).
#define CST(TE, SE, J) {                         \
    const float sg = rdlane(alpha, J);           \
    alpha += fexp2((TE) * sg);                   \
    beta  += fexp2((SE) * sg); }

#define CST4(tv, sv, J) \
    CST(tv.x, sv.x, J) CST(tv.y, sv.y, (J)+1) \
    CST(tv.z, sv.z, (J)+2) CST(tv.w, sv.w, (J)+3)

__global__ __launch_bounds__(NT)
void actr_kernel(const float* __restrict__ sp, const float* __restrict__ w,
                 float* __restrict__ out)
{
    __shared__ float  tH[L];
    __shared__ float  acc[L];        // far-field partial sums
    __shared__ float2 col[L];        // finalized columns {t_j, -decay_j}
    __shared__ float  qT[2][T * T];  // triangle q (j<l), swizzled
    __shared__ float  qS[2][T * T];  // strip tile S_b: rows blk b, cols blk b-1
    __shared__ int    COLF[16];
    __shared__ int    DONE[16];

    const int bid  = blockIdx.x;
    const int b    = (bid & 7) * 32 + (bid >> 3);   // XCD write-coalescing
    const int tid  = threadIdx.x;
    const int lane = tid & 63;
    const int wv   = tid >> 6;       // 0..7
    const float w0  = w[0];
    const float w1  = w[1];
    const float CSH = w0 / w1;

    for (int i = tid; i < L; i += NT) {
        tH[i]  = sp[i * B + b] * H_CONST;
        acc[i] = 0.0f;
    }
    if (tid < 16) { COLF[tid] = 0; DONE[tid] = 0; }
    __syncthreads();

    // prologue (all 8 waves): qT blocks 0,1; qS blocks 1,2
    for (int blk = 0; blk < 2; ++blk) {
        const int base = blk * 64;
        for (int f = tid; f < T * T; f += NT) {
            const int j = f & 63, l2 = f >> 6;
            const float val = -w1 * flog2(tH[base + l2] - tH[base + j]);
            qT[blk][l2 * 64 + (j ^ (4 * (l2 & 15)))] = (j < l2) ? val : BIGNEG;
        }
    }
    for (int sb = 1; sb <= 2; ++sb) {
        const int br = sb * 64, bc = (sb - 1) * 64;
        for (int f = tid; f < T * T; f += NT) {
            const int j = f & 63, i2 = f >> 6;
            qS[sb & 1][i2 * 64 + (j ^ (4 * (i2 & 15)))] =
                -w1 * flog2(tH[br + i2] - tH[bc + j]);
        }
    }
    __syncthreads();    // last barrier

    if (wv == 0) {
        // ================= chain wave (SIMD0, alone) =================
        volatile int* vDONE = DONE;
        const int xk = lane & 15;
        float beta = 0.0f;           // strip into the NEXT block
        for (int k = 0; k < 16; ++k) {
            const int I0 = k * T;
            const int target = (k <= 1) ? 0 : k + 5;   // (k-1) far + 6 build
            while (vDONE[k] < target) __builtin_amdgcn_s_sleep(2);
            asm volatile("" ::: "memory");

            const float* qbT = &qT[k & 1][lane * 64];
            const float* qbS = &qS[(k + 1) & 1][lane * 64];
            f32x4 t0, t1, t2, t3, t4, t5, t6, t7, t8, t9, tA, tB, tC, tD, tE, tF;
            f32x4 s0, s1, s2, s3, s4, s5, s6, s7, s8, s9, sA, sB, sC, sD, sE, sF;
            LOADQ(t0, t1, t2, t3, qbT, 0)
            LOADQ(s0, s1, s2, s3, qbS, 0)
            LOADQ(t4, t5, t6, t7, qbT, 1)
            LOADQ(s4, s5, s6, s7, qbS, 1)
            LOADQ(t8, t9, tA, tB, qbT, 2)
            LOADQ(s8, s9, sA, sB, qbS, 2)
            LOADQ(tC, tD, tE, tF, qbT, 3)
            LOADQ(sC, sD, sE, sF, qbS, 3)

            float alpha = acc[I0 + lane] + beta + CSH;
            beta = 0.0f;
            __builtin_amdgcn_s_setprio(1);
            CST4(t0, s0,  0) CST4(t1, s1,  4) CST4(t2, s2,  8) CST4(t3, s3, 12)
            CST4(t4, s4, 16) CST4(t5, s5, 20) CST4(t6, s6, 24) CST4(t7, s7, 28)
            CST4(t8, s8, 32) CST4(t9, s9, 36) CST4(tA, sA, 40) CST4(tB, sB, 44)
            CST4(tC, sC, 48) CST4(tD, sD, 52) CST4(tE, sE, 56) CST4(tF, sF, 60)
            __builtin_amdgcn_s_setprio(0);

            const int r = I0 + lane;
            col[r] = make_float2(tH[r], -w1 * alpha);   // alpha lane l = sigma_l
            asm volatile("" ::: "memory");
            if (lane == 0) atomicExch(&COLF[k], 1);     // release

            if (r > 0) {
                const float act = flog2(alpha - CSH) * LN2;     // ln(s_r)
                const float e   = fexp2((TAU_C - act) * (LOG2E / S_C));
                out[(r - 1) * B + b] = 1.0f / (1.0f + e);
            }
        }
    } else if (wv != 4) {
        // ================= 6 worker waves (never on SIMD0) =================
        const int p = (wv < 4) ? (wv - 1) : (wv - 2);   // 0..5
        volatile int* vCOLF = COLF;
        for (int c = 0; c < 14; ++c) {
            while (vCOLF[c] == 0) __builtin_amdgcn_s_sleep(2);
            asm volatile("" ::: "memory");

            // --- far tiles (r, c) via Chebyshev-8: r = c+2+p+6m ---
            #pragma unroll
            for (int t2 = 0; t2 < 3; ++t2) {
                const int r = c + 2 + p + 6 * t2;
                if (r <= 15) {
                    const int m  = lane >> 3;
                    const int g  = lane & 7;
                    const float At  = tH[r * 64];
                    const float Bt  = tH[r * 64 + 63];
                    const float mid = 0.5f * (At + Bt);
                    const float hf  = 0.5f * (Bt - At);
                    const float xm  = fmaf(hf, UNODE[m], mid);
                    const float2* cb = &col[c * 64 + g * 8];
                    float gm = 0.0f;
                    #pragma unroll
                    for (int jj = 0; jj < 8; ++jj) {
                        const float2 cj = cb[jj];
                        gm += fexp2(cj.y * flog2(xm - cj.x));
                    }
                    gm += __shfl_xor(gm, 1);
                    gm += __shfl_xor(gm, 2);
                    gm += __shfl_xor(gm, 4);
                    const float g0 = rdlane(gm,  0), g1 = rdlane(gm,  8);
                    const float g2 = rdlane(gm, 16), g3 = rdlane(gm, 24);
                    const float g4 = rdlane(gm, 32), g5 = rdlane(gm, 40);
                    const float g6 = rdlane(gm, 48), g7 = rdlane(gm, 56);
                    const float s0 = g0 + g7, s1 = g1 + g6;
                    const float s2 = g2 + g5, s3 = g3 + g4;
                    const float d0 = g0 - g7, d1 = g1 - g6;
                    const float d2 = g2 - g5, d3 = g3 - g4;
                    const float a0 = 0.125f * (s0 + s1 + s2 + s3);
                    const float a2 = 0.25f * (CC2 * (s0 - s3) + CC6 * (s1 - s2));
                    const float a4 = 0.25f * CC4 * (s0 - s1 - s2 + s3);
                    const float a6 = 0.25f * (CC6 * (s0 - s3) - CC2 * (s1 - s2));
                    const float a1 = 0.25f * (CC1*d0 + CC3*d1 + CC5*d2 + CC7*d3);
                    const float a3 = 0.25f * (CC3*d0 - CC7*d1 - CC1*d2 - CC5*d3);
                    const float a5 = 0.25f * (CC5*d0 - CC1*d1 + CC7*d2 + CC3*d3);
                    const float a7 = 0.25f * (CC7*d0 - CC5*d1 + CC3*d2 - CC1*d3);
                    const int   i  = r * 64 + lane;
                    const float u  = (tH[i] - mid) * __builtin_amdgcn_rcpf(hf);
                    const float u2 = u + u;
                    float bk1 = a7;
                    float bk  = fmaf(u2, a7, a6);
                    float t3;
                    t3 = fmaf(u2, bk, a5) - bk1; bk1 = bk; bk = t3;
                    t3 = fmaf(u2, bk, a4) - bk1; bk1 = bk; bk = t3;
                    t3 = fmaf(u2, bk, a3) - bk1; bk1 = bk; bk = t3;
                    t3 = fmaf(u2, bk, a2) - bk1; bk1 = bk; bk = t3;
                    t3 = fmaf(u2, bk, a1) - bk1; bk1 = bk; bk = t3;
                    atomicAdd(&acc[i], fmaf(u, bk, a0) - bk1);
                    asm volatile("" ::: "memory");
                    if (lane == 0) atomicAdd(&DONE[r], 1);
                }
            }

            // --- build qT[c+2] and qS[c+3] (timestamps only) ---
            {
                const int blk  = c + 2;
                const float vtB = tH[blk * 64 + lane];          // block c+2
                float* qnT = &qT[blk & 1][0];
                #pragma unroll
                for (int m2 = 0; m2 < 11; ++m2) {
                    const int l2 = p + 6 * m2;
                    if (l2 < 64) {
                        const float tl2 = rdlane(vtB, l2);
                        const float val = -w1 * flog2(tl2 - vtB);
                        qnT[l2 * 64 + (lane ^ (4 * (l2 & 15)))] =
                            (lane < l2) ? val : BIGNEG;
                    }
                }
                if (c <= 12) {      // S_{c+3}: rows block c+3, cols block c+2
                    const float vtC = tH[(c + 3) * 64 + lane];
                    float* qnS = &qS[(c + 3) & 1][0];
                    #pragma unroll
                    for (int m2 = 0; m2 < 11; ++m2) {
                        const int i2 = p + 6 * m2;
                        if (i2 < 64) {
                            const float tri = rdlane(vtC, i2);
                            qnS[i2 * 64 + (lane ^ (4 * (i2 & 15)))] =
                                -w1 * flog2(tri - vtB);
                        }
                    }
                }
                asm volatile("" ::: "memory");
                if (lane == 0) atomicAdd(&DONE[blk], 1);
            }
        }
    }
    // wave 4: idle — SIMD0 belongs to the chain
}

extern "C" void kernel_launch(void* const* d_in, const int* in_sizes, int n_in,
                              void* d_out, int out_size, void* d_ws, size_t ws_size,
                              hipStream_t stream) {
    const float* sp = (const float*)d_in[0];
    const float* w  = (const float*)d_in[1];
    float* out      = (float*)d_out;
    actr_kernel<<<dim3(B), dim3(NT), 0, stream>>>(sp, w, out);
}